// Round 5
// baseline (2373.749 us; speedup 1.0000x reference)
//
#include <hip/hip_runtime.h>
#include <math.h>

// HybridDecoder. B=1024 H=1024 IN=512 OUT=8192 T=15.
// R5: gemm256 rebalanced (2-phase/K-tile, frags read once -> LDS pipe == MFMA pipe);
//     GRU: dec-part of gi hoisted to one parallel GEMM (gdec), cell+h2x fused.
// conv_transpose identity: y[n,o,t] = sum_{2l+k=t} x[n,i,l] * W[o,i,k]

#define HD    1024
#define BATCH 1024
#define IND   512
#define OUTD  8192
#define TSTEPS 15
#define EPSV  1e-5f

typedef unsigned short u16;
typedef __attribute__((ext_vector_type(8))) short bf16x8;
typedef __attribute__((ext_vector_type(8))) unsigned short u16x8;
typedef __attribute__((ext_vector_type(4))) float f32x4;

__device__ __forceinline__ u16 f2b(float f) {          // fp32 -> bf16 RNE
    union { float f; unsigned u; } x; x.f = f;
    unsigned r = x.u + 0x7fffu + ((x.u >> 16) & 1u);
    return (u16)(r >> 16);
}

typedef __attribute__((address_space(1))) const void gas_t;
typedef __attribute__((address_space(3))) void las_t;
__device__ __forceinline__ void gload_lds16(const u16* g, u16* l) {
    __builtin_amdgcn_global_load_lds((gas_t*)g, (las_t*)l, 16, 0, 0);
}

// ===========================================================================
// 256x256 GEMM (bf16 in, fp32 out): C = A@B^T + bias.
// 512 thr = 8 waves (2M x 4N); BK=64 double-buffered (128 KiB LDS).
// 2 phases/K-tile: each reads its 12 frags ONCE and does 32 MFMA.
// XOR swizzle on global-source + ds_read (Guideline 21 both-sides).
// ===========================================================================
__launch_bounds__(512, 2)
__global__ void gemm256(int nbn, int nk,
    const u16* __restrict__ A, const u16* __restrict__ B,
    const float* __restrict__ bias, float* __restrict__ C,
    int lda, int ldb, int ldc)
{
    // bijective XCD swizzle (m204)
    const int nwg = gridDim.x;
    const int q = nwg >> 3, r = nwg & 7;
    const int xcd = blockIdx.x & 7, idx = blockIdx.x >> 3;
    const int wg = (xcd < r ? xcd * (q + 1) : r * (q + 1) + (xcd - r) * q) + idx;
    const int bm = (wg / nbn) * 256;
    const int bn = (wg % nbn) * 256;

    __shared__ __align__(16) u16 As[2][256 * 64];
    __shared__ __align__(16) u16 Bs[2][256 * 64];

    const int tid = threadIdx.x;
    const int w = tid >> 6, l = tid & 63;
    const int wr = w >> 2, wc = w & 3;       // 2M x 4N wave grid
    const int srow = l >> 3;                 // staging row in 8-row chunk
    const int scb  = (l & 7) ^ srow;         // swizzled SOURCE col-block
    const int fr = l & 15, fcb = l >> 4, swz = l & 7;

    const u16* Ag = A + (size_t)bm * lda;
    const u16* Bg = B + (size_t)bn * ldb;

    auto stage = [&](int b, int kt) {        // 8 gload_lds / thread
        const int k0 = kt * 64 + scb * 8;
#pragma unroll
        for (int rr = 0; rr < 4; ++rr)
            gload_lds16(Ag + (size_t)(rr * 64 + w * 8 + srow) * lda + k0,
                        &As[b][(rr * 64 + w * 8) * 64]);
#pragma unroll
        for (int rr = 0; rr < 4; ++rr)
            gload_lds16(Bg + (size_t)(rr * 64 + w * 8 + srow) * ldb + k0,
                        &Bs[b][(rr * 64 + w * 8) * 64]);
    };

    f32x4 acc[8][4];
#pragma unroll
    for (int m = 0; m < 8; ++m)
#pragma unroll
        for (int n = 0; n < 4; ++n) acc[m][n] = (f32x4){0.f, 0.f, 0.f, 0.f};

    stage(0, 0);
    asm volatile("s_waitcnt vmcnt(0)" ::: "memory");
    asm volatile("s_barrier" ::: "memory");

    for (int kt = 0; kt < nk; ++kt) {
        const int c = kt & 1;
#pragma unroll
        for (int ks = 0; ks < 2; ++ks) {
            bf16x8 av[8], bv[4];
#pragma unroll
            for (int m = 0; m < 8; ++m)
                av[m] = *(const bf16x8*)&As[c][
                    (wr * 128 + m * 16 + fr) * 64 + (((ks * 4 + fcb) ^ swz) * 8)];
#pragma unroll
            for (int n = 0; n < 4; ++n)
                bv[n] = *(const bf16x8*)&Bs[c][
                    (wc * 64 + n * 16 + fr) * 64 + (((ks * 4 + fcb) ^ swz) * 8)];
            if (ks == 0 && kt + 1 < nk) stage(c ^ 1, kt + 1);  // ~1.5-phase lead
            __builtin_amdgcn_s_setprio(1);
#pragma unroll
            for (int m = 0; m < 8; ++m)
#pragma unroll
                for (int n = 0; n < 4; ++n)
                    acc[m][n] = __builtin_amdgcn_mfma_f32_16x16x32_bf16(
                                    av[m], bv[n], acc[m][n], 0, 0, 0);
            __builtin_amdgcn_s_setprio(0);
            if (ks == 1)   // own stages done -> barrier makes them globally visible
                asm volatile("s_waitcnt vmcnt(0)" ::: "memory");
            asm volatile("s_barrier" ::: "memory");
        }
    }

    // epilogue: C/D layout col=lane&15, row=(lane>>4)*4+j
    const int row_h = (l >> 4) * 4;
#pragma unroll
    for (int m = 0; m < 8; ++m) {
#pragma unroll
        for (int j = 0; j < 4; ++j) {
            const int row = bm + wr * 128 + m * 16 + row_h + j;
#pragma unroll
            for (int n = 0; n < 4; ++n) {
                const int col = bn + wc * 64 + n * 16 + fr;
                C[(size_t)row * ldc + col] = acc[m][n][j] + bias[col];
            }
        }
    }
}

// ===========================================================================
// 128x128 m97-structure tile for conv / GRU GEMMs (+ optional fp32 C-init)
// ===========================================================================
template<int EPI, bool WF32, bool WB16>
__device__ __forceinline__ void gemm_tile(
    int bm, int bn,
    int K1, const u16* A1, int lda1, const u16* B1, int ldb1,
    int K2, const u16* A2, int lda2, const u16* B2, int ldb2,
    const float* bias, const float* Cin,
    const float* bng, const float* bnb, const float* bnm, const float* bnv,
    float* Cf, u16* Cb, int ldc)
{
    __shared__ __align__(16) u16 As[128 * 32];
    __shared__ __align__(16) u16 Bs[128 * 32];

    const int tid  = threadIdx.x;
    const int lane = tid & 63;
    const int w    = tid >> 6;
    const int wr   = w >> 1, wc = w & 1;
    const int r_in = lane >> 2;
    const int c_in = (lane & 3) * 8;

    f32x4 acc[4][4];
#pragma unroll
    for (int m = 0; m < 4; ++m)
#pragma unroll
        for (int n = 0; n < 4; ++n) acc[m][n] = (f32x4){0.f, 0.f, 0.f, 0.f};

#pragma unroll 1
    for (int pair = 0; pair < 2; ++pair) {
        const int K = pair ? K2 : K1;
        if (K == 0) continue;
        const int lda = pair ? lda2 : lda1;
        const int ldb = pair ? ldb2 : ldb1;
        const u16* Ag = (pair ? A2 : A1) + (size_t)bm * lda;
        const u16* Bg = (pair ? B2 : B1) + (size_t)bn * ldb;

        for (int k0 = 0; k0 < K; k0 += 32) {
#pragma unroll
            for (int i = 0; i < 2; ++i) {
                gload_lds16(Ag + (size_t)(i * 64 + w * 16 + r_in) * lda + k0 + c_in,
                            &As[i * 2048 + w * 512]);
                gload_lds16(Bg + (size_t)(i * 64 + w * 16 + r_in) * ldb + k0 + c_in,
                            &Bs[i * 2048 + w * 512]);
            }
            __syncthreads();

            const int fr = lane & 15;
            const int fk = (lane >> 4) * 8;
            bf16x8 av[4], bv[4];
#pragma unroll
            for (int m = 0; m < 4; ++m)
                av[m] = *(const bf16x8*)&As[(wr * 64 + m * 16 + fr) * 32 + fk];
#pragma unroll
            for (int n = 0; n < 4; ++n)
                bv[n] = *(const bf16x8*)&Bs[(wc * 64 + n * 16 + fr) * 32 + fk];
#pragma unroll
            for (int m = 0; m < 4; ++m)
#pragma unroll
                for (int n = 0; n < 4; ++n)
                    acc[m][n] = __builtin_amdgcn_mfma_f32_16x16x32_bf16(
                                    av[m], bv[n], acc[m][n], 0, 0, 0);
            __syncthreads();
        }
    }

    const int col_l = lane & 15;
    const int row_h = (lane >> 4) * 4;
#pragma unroll
    for (int m = 0; m < 4; ++m) {
#pragma unroll
        for (int j = 0; j < 4; ++j) {
            const int row = bm + wr * 64 + m * 16 + row_h + j;
#pragma unroll
            for (int n = 0; n < 4; ++n) {
                const int col = bn + wc * 64 + n * 16 + col_l;
                float v = acc[m][n][j];
                if (Cin)  v += Cin[(size_t)row * ldc + col];
                if (bias) v += bias[col];
                if (EPI == 1) {
                    float e = v > 0.f ? v : expm1f(v);
                    float sc = bng[col] * rsqrtf(bnv[col] + EPSV);
                    v = (e - bnm[col]) * sc + bnb[col];
                } else if (EPI == 2) {
                    v = fmaxf(v, 0.f);
                }
                if (WF32) Cf[(size_t)row * ldc + col] = v;
                if (WB16) Cb[(size_t)row * ldc + col] = f2b(v);
            }
        }
    }
}

template<int EPI>
__launch_bounds__(256)
__global__ void conv_gemm(int Lin, const u16* X, const u16* W, const float* bias,
                          const float* bng, const float* bnb, const float* bnm, const float* bnv,
                          u16* Y)
{
    const int t = blockIdx.z;
    int l0 = 0, k0 = 0, l1 = 0, k1 = 0, cnt = 0;
    for (int l = 0; l < Lin; ++l) {
        int k = t - 2 * l;
        if (k >= 0 && k < 3) { if (!cnt) { l0 = l; k0 = k; } else { l1 = l; k1 = k; } ++cnt; }
    }
    const size_t BH = (size_t)BATCH * HD, HH = (size_t)HD * HD;
    gemm_tile<EPI, false, true>(blockIdx.y * 128, blockIdx.x * 128,
        HD, X + l0 * BH, HD, W + k0 * HH, HD,
        cnt > 1 ? HD : 0, X + l1 * BH, HD, W + k1 * HH, HD,
        bias, nullptr, bng, bnb, bnm, bnv, nullptr, Y + (size_t)t * BH, HD);
}

// gi (z=0, K=512 from inp, C-init = gdec_t) and gh (z=1, K=1024) in one launch
__launch_bounds__(256)
__global__ void gru_gemms(int K_gi, const u16* inp_b, const u16* w_ih_b,
                          const u16* h_b, const u16* w_hh_b,
                          const float* gdec_t, const float* bias_gi,
                          const float* b_hh, float* gi, float* gh)
{
    if (blockIdx.z == 0)
        gemm_tile<0, true, false>(blockIdx.y * 128, blockIdx.x * 128,
            K_gi, inp_b, IND, w_ih_b, IND + HD,
            0, nullptr, 0, nullptr, 0,
            bias_gi, gdec_t, nullptr, nullptr, nullptr, nullptr,
            gi, nullptr, 3 * HD);
    else
        gemm_tile<0, true, false>(blockIdx.y * 128, blockIdx.x * 128,
            HD, h_b, HD, w_hh_b, HD,
            0, nullptr, 0, nullptr, 0,
            b_hh, nullptr, nullptr, nullptr, nullptr, nullptr,
            gh, nullptr, 3 * HD);
}

// ===========================================================================
// fused GRU cell + h2x projection. Block = 16 batch rows, 512 thr (8 waves).
// Phase1: pointwise cell -> h (fp32 global, bf16 global, bf16 LDS swizzled).
// Phase2: inp = relu(h @ h2xw^T + b) via MFMA (M=16, N=512, K=1024).
// ===========================================================================
__launch_bounds__(512)
__global__ void cell_h2x(const float* __restrict__ gi, const float* __restrict__ gh,
                         const float* __restrict__ hp, float* __restrict__ hf,
                         u16* __restrict__ hb, const u16* __restrict__ wx,
                         const float* __restrict__ xb, u16* __restrict__ inp,
                         int last)
{
    __shared__ __align__(16) u16 hl[16 * 1024];
    const int n0 = blockIdx.x * 16;
    const int tid = threadIdx.x;

#pragma unroll 4
    for (int j = 0; j < 32; ++j) {
        const int idx = j * 512 + tid;           // 0..16383
        const int row = idx >> 10, col = idx & 1023;
        const size_t base = (size_t)(n0 + row) * (3 * HD) + col;
        const float ir = gi[base], iz = gi[base + HD], in_ = gi[base + 2 * HD];
        const float hr = gh[base], hz = gh[base + HD], hn = gh[base + 2 * HD];
        const float rg = 1.f / (1.f + expf(-(ir + hr)));
        const float zg = 1.f / (1.f + expf(-(iz + hz)));
        const float nn = tanhf(in_ + rg * hn);
        const float h  = (1.f - zg) * nn + zg * hp[(size_t)(n0 + row) * HD + col];
        hf[(size_t)(n0 + row) * HD + col] = h;
        const u16 hv = f2b(h);
        hb[(size_t)(n0 + row) * HD + col] = hv;
        const int cb = col >> 3;
        hl[row * 1024 + ((cb ^ (row & 7)) << 3) + (col & 7)] = hv;   // swizzled
    }
    __syncthreads();
    if (last) return;

    const int l = tid & 63, w = tid >> 6;
    const int fr = l & 15, fk4 = l >> 4;
    f32x4 acc[4];
#pragma unroll
    for (int n = 0; n < 4; ++n) acc[n] = (f32x4){0.f, 0.f, 0.f, 0.f};

    for (int ks = 0; ks < 32; ++ks) {
        const int kc = ks * 4 + fk4;             // 8-wide k col-block
        const bf16x8 av = *(const bf16x8*)&hl[fr * 1024 + ((kc ^ (fr & 7)) << 3)];
#pragma unroll
        for (int nf = 0; nf < 4; ++nf) {
            const int brow = w * 64 + nf * 16 + fr;
            const bf16x8 bv = *(const bf16x8*)&wx[(size_t)brow * HD + kc * 8];
            acc[nf] = __builtin_amdgcn_mfma_f32_16x16x32_bf16(av, bv, acc[nf], 0, 0, 0);
        }
    }
    const int row_h = (l >> 4) * 4;
#pragma unroll
    for (int nf = 0; nf < 4; ++nf) {
#pragma unroll
        for (int j = 0; j < 4; ++j) {
            const int rr = row_h + j;
            const int cc = w * 64 + nf * 16 + fr;
            const float v = fmaxf(acc[nf][j] + xb[cc], 0.f);
            inp[(size_t)(n0 + rr) * IND + cc] = f2b(v);
        }
    }
}

// ---------------------------------------------------------------------------
__global__ void pack_w(const float* __restrict__ cw, u16* __restrict__ wp)
{   // (H,H,3) raw [o,i,k] -> bf16 (3,H,H) [k][o][i]
    __shared__ float lds[768];
    const int o = blockIdx.x, t = threadIdx.x;
    const float* src = cw + (size_t)o * (HD * 3);
    for (int i0 = 0; i0 < HD; i0 += 256) {
#pragma unroll
        for (int r = 0; r < 3; ++r) lds[t + 256 * r] = src[i0 * 3 + t + 256 * r];
        __syncthreads();
#pragma unroll
        for (int k = 0; k < 3; ++k)
            wp[(size_t)k * HD * HD + (size_t)o * HD + i0 + t] = f2b(lds[t * 3 + k]);
        __syncthreads();
    }
}

__global__ void f32_to_b16(const float* __restrict__ s, u16* __restrict__ d, int n)
{
    int i = (blockIdx.x * 256 + threadIdx.x) * 8;
    if (i >= n) return;
    float4 a = *(const float4*)(s + i);
    float4 b = *(const float4*)(s + i + 4);
    u16x8 o;
    o[0] = f2b(a.x); o[1] = f2b(a.y); o[2] = f2b(a.z); o[3] = f2b(a.w);
    o[4] = f2b(b.x); o[5] = f2b(b.y); o[6] = f2b(b.z); o[7] = f2b(b.w);
    *(u16x8*)(d + i) = o;
}

// extra0[j] = 8190 * sum_{k<IND} w_ih[j,k]  (fp32-exact t=0 inp contribution)
__global__ void ext0_k(const float* __restrict__ w_ih, float* __restrict__ e0)
{
    const int j = blockIdx.x, lane = threadIdx.x;   // 64 lanes
    float s = 0.f;
    for (int k = lane; k < IND; k += 64) s += w_ih[(size_t)j * (IND + HD) + k];
    for (int off = 32; off; off >>= 1) s += __shfl_down(s, off);
    if (lane == 0) e0[j] = 8190.f * s;
}

// ---------------------------------------------------------------------------
extern "C" void kernel_launch(void* const* d_in, const int* in_sizes, int n_in,
                              void* d_out, int out_size, void* d_ws, size_t ws_size,
                              hipStream_t stream)
{
    (void)in_sizes; (void)n_in; (void)out_size; (void)ws_size;

    const float* z    = (const float*)d_in[0];
    const float* cw1  = (const float*)d_in[2];
    const float* cb1  = (const float*)d_in[3];
    const float* cw2  = (const float*)d_in[4];
    const float* cb2  = (const float*)d_in[5];
    const float* cw3  = (const float*)d_in[6];
    const float* cb3  = (const float*)d_in[7];
    const float* bn1g = (const float*)d_in[8];
    const float* bn1b = (const float*)d_in[9];
    const float* bn1m = (const float*)d_in[10];
    const float* bn1v = (const float*)d_in[11];
    const float* bn2g = (const float*)d_in[12];
    const float* bn2b = (const float*)d_in[13];
    const float* bn2m = (const float*)d_in[14];
    const float* bn2v = (const float*)d_in[15];
    const float* w_ih = (const float*)d_in[16];
    const float* w_hh = (const float*)d_in[17];
    const float* b_ih = (const float*)d_in[18];
    const float* b_hh = (const float*)d_in[19];
    const float* h2xw = (const float*)d_in[20];
    const float* h2xb = (const float*)d_in[21];
    const float* d2ow = (const float*)d_in[22];
    const float* d2ob = (const float*)d_in[23];
    const float* outw = (const float*)d_in[24];
    const float* outb = (const float*)d_in[25];

    const size_t HH = (size_t)HD * HD, BH = (size_t)BATCH * HD;
    const size_t B3H = (size_t)BATCH * 3 * HD;

    u16* wsb = (u16*)d_ws;
    size_t off = 0;
    auto A16 = [&](size_t n) { u16* p = wsb + off; off += n; return p; };
    u16* wp1   = A16(3 * HH);
    u16* wp2   = A16(3 * HH);
    u16* wp3   = A16(3 * HH);
    u16* wihb  = A16((size_t)3 * HD * (IND + HD));
    u16* whhb  = A16(3 * HH);
    u16* h2xbw = A16((size_t)IND * HD);
    u16* outwb = A16((size_t)OUTD * HD);
    u16* d2owb = A16((size_t)OUTD * HD);
    u16* zb    = A16(BH);
    u16* decab = A16(3 * BH);
    u16* decbb = A16(7 * BH);
    u16* dec3b = A16(15 * BH);
    u16* hsb   = A16(15 * BH);
    u16* inpb  = A16((size_t)BATCH * IND);
    float* wsf = (float*)(wsb + ((off + 1) & ~(size_t)1));
    size_t foff = 0;
    auto A32 = [&](size_t n) { float* p = wsf + foff; foff += n; return p; };
    float* gi    = A32(B3H);
    float* gh    = A32(B3H);
    float* h0f   = A32(BH);
    float* h1f   = A32(BH);
    float* extra0= A32(3 * HD);
    float* gdec  = A32((size_t)TSTEPS * B3H);   // 15 x 1024 x 3072 fp32 (~188 MB)

    pack_w<<<HD, 256, 0, stream>>>(cw1, wp1);
    pack_w<<<HD, 256, 0, stream>>>(cw2, wp2);
    pack_w<<<HD, 256, 0, stream>>>(cw3, wp3);
    auto cvt = [&](const float* s, u16* d, size_t n) {
        f32_to_b16<<<(unsigned)(n / 2048), 256, 0, stream>>>(s, d, (int)n);
    };
    cvt(z, zb, BH);
    cvt(w_ih, wihb, (size_t)3 * HD * (IND + HD));
    cvt(w_hh, whhb, 3 * HH);
    cvt(h2xw, h2xbw, (size_t)IND * HD);
    cvt(outw, outwb, (size_t)OUTD * HD);
    cvt(d2ow, d2owb, (size_t)OUTD * HD);
    ext0_k<<<3 * HD, 64, 0, stream>>>(w_ih, extra0);

    conv_gemm<1><<<dim3(8, 8, 3), 256, 0, stream>>>(1, zb, wp1, cb1,
        bn1g, bn1b, bn1m, bn1v, decab);
    conv_gemm<1><<<dim3(8, 8, 7), 256, 0, stream>>>(3, decab, wp2, cb2,
        bn2g, bn2b, bn2m, bn2v, decbb);
    conv_gemm<0><<<dim3(8, 8, 15), 256, 0, stream>>>(7, decbb, wp3, cb3,
        nullptr, nullptr, nullptr, nullptr, dec3b);

    // gdec[t] = dec_tbh @ w_ih[:,512:]^T + b_ih  for all t (parallel, off the chain)
    gemm256<<<dim3((TSTEPS * BATCH / 256) * (3 * HD / 256)), 512, 0, stream>>>(
        3 * HD / 256, HD / 64,
        dec3b, wihb + IND, b_ih, gdec, HD, IND + HD, 3 * HD);

    for (int t = 0; t < TSTEPS; ++t) {
        const u16* hbp   = t ? hsb + (size_t)(t - 1) * BH : zb;
        const float* hpf = (t == 0) ? z : (((t - 1) & 1) ? h1f : h0f);
        float* hwf = (t & 1) ? h1f : h0f;
        gru_gemms<<<dim3(24, 8, 2), 256, 0, stream>>>(
            t ? IND : 0, inpb, wihb, hbp, whhb,
            gdec + (size_t)t * B3H, t ? nullptr : extra0, b_hh, gi, gh);
        cell_h2x<<<BATCH / 16, 512, 0, stream>>>(gi, gh, hpf, hwf,
            hsb + (size_t)t * BH, h2xbw, h2xb, inpb, t == TSTEPS - 1);
    }

    // output projections
    float* out0 = (float*)d_out;
    float* out1 = out0 + (size_t)TSTEPS * BATCH * OUTD;
    const int nbn = OUTD / 256;                       // 32
    const int nwg = (TSTEPS * BATCH / 256) * nbn;     // 1920
    gemm256<<<dim3(nwg), 512, 0, stream>>>(nbn, HD / 64,
        hsb, outwb, outb, out0, HD, HD, OUTD);
    gemm256<<<dim3(nwg), 512, 0, stream>>>(nbn, HD / 64,
        dec3b, d2owb, d2ob, out1, HD, HD, OUTD);
}

// Round 6
// 2106.926 us; speedup vs baseline: 1.1266x; 1.1266x over previous
//
#include <hip/hip_runtime.h>
#include <math.h>

// HybridDecoder. B=1024 H=1024 IN=512 OUT=8192 T=15.
// R6: gemm256 = 1 barrier/K-tile, stage hoisted to tile top (full-tile vmcnt cover),
//     LDS-transposed coalesced fp32 epilogue. GRU chain back to cell(4096 blk)+h2x(32 blk).
// conv_transpose identity: y[n,o,t] = sum_{2l+k=t} x[n,i,l] * W[o,i,k]

#define HD    1024
#define BATCH 1024
#define IND   512
#define OUTD  8192
#define TSTEPS 15
#define EPSV  1e-5f

typedef unsigned short u16;
typedef __attribute__((ext_vector_type(8))) short bf16x8;
typedef __attribute__((ext_vector_type(8))) unsigned short u16x8;
typedef __attribute__((ext_vector_type(4))) float f32x4;

__device__ __forceinline__ u16 f2b(float f) {          // fp32 -> bf16 RNE
    union { float f; unsigned u; } x; x.f = f;
    unsigned r = x.u + 0x7fffu + ((x.u >> 16) & 1u);
    return (u16)(r >> 16);
}

typedef __attribute__((address_space(1))) const void gas_t;
typedef __attribute__((address_space(3))) void las_t;
__device__ __forceinline__ void gload_lds16(const u16* g, u16* l) {
    __builtin_amdgcn_global_load_lds((gas_t*)g, (las_t*)l, 16, 0, 0);
}

// ===========================================================================
// 256x256 GEMM (bf16 in, fp32 out): C = A@B^T + bias.
// 512 thr = 8 waves (2M x 4N); BK=64 double-buffered (128 KiB LDS).
// Per K-tile: stage(kt+1) issued FIRST -> 24 b128 frag reads + 64 MFMA cover
// the loads -> single {vmcnt(0); s_barrier} per tile.
// XOR swizzle on global-source + ds_read (Guideline 21 both-sides).
// Epilogue: acc -> LDS(f32) -> coalesced float4 streams (2 halves).
// ===========================================================================
__launch_bounds__(512, 2)
__global__ void gemm256(int nbn, int nk,
    const u16* __restrict__ A, const u16* __restrict__ B,
    const float* __restrict__ bias, float* __restrict__ C,
    int lda, int ldb, int ldc)
{
    // bijective XCD swizzle (m204)
    const int nwg = gridDim.x;
    const int q = nwg >> 3, r = nwg & 7;
    const int xcd = blockIdx.x & 7, idx = blockIdx.x >> 3;
    const int wg = (xcd < r ? xcd * (q + 1) : r * (q + 1) + (xcd - r) * q) + idx;
    const int bm = (wg / nbn) * 256;
    const int bn = (wg % nbn) * 256;

    __shared__ __align__(16) u16 smem[2][2][256 * 64];   // [A/B][buf][.]
    u16 (*As)[256 * 64] = smem[0];
    u16 (*Bs)[256 * 64] = smem[1];

    const int tid = threadIdx.x;
    const int w = tid >> 6, l = tid & 63;
    const int wr = w >> 2, wc = w & 3;       // 2M x 4N wave grid
    const int srow = l >> 3;                 // staging row in 8-row chunk
    const int scb  = (l & 7) ^ srow;         // swizzled SOURCE col-block
    const int fr = l & 15, fcb = l >> 4, swz = l & 7;

    const u16* Ag = A + (size_t)bm * lda;
    const u16* Bg = B + (size_t)bn * ldb;

    auto stage = [&](int b, int kt) {        // 8 gload_lds / thread
        const int k0 = kt * 64 + scb * 8;
#pragma unroll
        for (int rr = 0; rr < 4; ++rr)
            gload_lds16(Ag + (size_t)(rr * 64 + w * 8 + srow) * lda + k0,
                        &As[b][(rr * 64 + w * 8) * 64]);
#pragma unroll
        for (int rr = 0; rr < 4; ++rr)
            gload_lds16(Bg + (size_t)(rr * 64 + w * 8 + srow) * ldb + k0,
                        &Bs[b][(rr * 64 + w * 8) * 64]);
    };

    f32x4 acc[8][4];
#pragma unroll
    for (int m = 0; m < 8; ++m)
#pragma unroll
        for (int n = 0; n < 4; ++n) acc[m][n] = (f32x4){0.f, 0.f, 0.f, 0.f};

    stage(0, 0);
    asm volatile("s_waitcnt vmcnt(0)" ::: "memory");
    asm volatile("s_barrier" ::: "memory");

    for (int kt = 0; kt < nk; ++kt) {
        const int c = kt & 1;
        if (kt + 1 < nk) stage(c ^ 1, kt + 1);    // full-tile cover before wait
#pragma unroll
        for (int ks = 0; ks < 2; ++ks) {
            bf16x8 av[8], bv[4];
#pragma unroll
            for (int m = 0; m < 8; ++m)
                av[m] = *(const bf16x8*)&As[c][
                    (wr * 128 + m * 16 + fr) * 64 + (((ks * 4 + fcb) ^ swz) * 8)];
#pragma unroll
            for (int n = 0; n < 4; ++n)
                bv[n] = *(const bf16x8*)&Bs[c][
                    (wc * 64 + n * 16 + fr) * 64 + (((ks * 4 + fcb) ^ swz) * 8)];
            __builtin_amdgcn_s_setprio(1);
#pragma unroll
            for (int m = 0; m < 8; ++m)
#pragma unroll
                for (int n = 0; n < 4; ++n)
                    acc[m][n] = __builtin_amdgcn_mfma_f32_16x16x32_bf16(
                                    av[m], bv[n], acc[m][n], 0, 0, 0);
            __builtin_amdgcn_s_setprio(0);
        }
        asm volatile("s_waitcnt vmcnt(0)" ::: "memory");   // kt+1 staged
        asm volatile("s_barrier" ::: "memory");            // all reads of c done
    }

    // ---- epilogue: LDS transpose -> coalesced fp32 streams ----
    float* fsm = (float*)smem;               // 128 x 256 f32 = 128 KiB
    const int row_h = (l >> 4) * 4;
#pragma unroll 1
    for (int hh = 0; hh < 2; ++hh) {
        __syncthreads();
        if (wr == hh) {
#pragma unroll
            for (int m = 0; m < 8; ++m)
#pragma unroll
                for (int j = 0; j < 4; ++j) {
                    const int rl = m * 16 + row_h + j;
#pragma unroll
                    for (int n = 0; n < 4; ++n)
                        fsm[rl * 256 + wc * 64 + n * 16 + fr] = acc[m][n][j];
                }
        }
        __syncthreads();
#pragma unroll
        for (int it = 0; it < 16; ++it) {
            const int fid = it * 512 + tid;          // 0..8191 float4 ids
            const int rl = fid >> 6;
            const int cf = (fid & 63) * 4;
            float4 v = *(const float4*)&fsm[rl * 256 + cf];
            v.x += bias[bn + cf + 0];
            v.y += bias[bn + cf + 1];
            v.z += bias[bn + cf + 2];
            v.w += bias[bn + cf + 3];
            *(float4*)&C[(size_t)(bm + hh * 128 + rl) * ldc + bn + cf] = v;
        }
    }
}

// ===========================================================================
// 128x128 m97-structure tile for conv / GRU GEMMs (+ optional fp32 C-init)
// ===========================================================================
template<int EPI, bool WF32, bool WB16>
__device__ __forceinline__ void gemm_tile(
    int bm, int bn,
    int K1, const u16* A1, int lda1, const u16* B1, int ldb1,
    int K2, const u16* A2, int lda2, const u16* B2, int ldb2,
    const float* bias, const float* Cin,
    const float* bng, const float* bnb, const float* bnm, const float* bnv,
    float* Cf, u16* Cb, int ldc)
{
    __shared__ __align__(16) u16 As[128 * 32];
    __shared__ __align__(16) u16 Bs[128 * 32];

    const int tid  = threadIdx.x;
    const int lane = tid & 63;
    const int w    = tid >> 6;
    const int wr   = w >> 1, wc = w & 1;
    const int r_in = lane >> 2;
    const int c_in = (lane & 3) * 8;

    f32x4 acc[4][4];
#pragma unroll
    for (int m = 0; m < 4; ++m)
#pragma unroll
        for (int n = 0; n < 4; ++n) acc[m][n] = (f32x4){0.f, 0.f, 0.f, 0.f};

#pragma unroll 1
    for (int pair = 0; pair < 2; ++pair) {
        const int K = pair ? K2 : K1;
        if (K == 0) continue;
        const int lda = pair ? lda2 : lda1;
        const int ldb = pair ? ldb2 : ldb1;
        const u16* Ag = (pair ? A2 : A1) + (size_t)bm * lda;
        const u16* Bg = (pair ? B2 : B1) + (size_t)bn * ldb;

        for (int k0 = 0; k0 < K; k0 += 32) {
#pragma unroll
            for (int i = 0; i < 2; ++i) {
                gload_lds16(Ag + (size_t)(i * 64 + w * 16 + r_in) * lda + k0 + c_in,
                            &As[i * 2048 + w * 512]);
                gload_lds16(Bg + (size_t)(i * 64 + w * 16 + r_in) * ldb + k0 + c_in,
                            &Bs[i * 2048 + w * 512]);
            }
            __syncthreads();

            const int fr = lane & 15;
            const int fk = (lane >> 4) * 8;
            bf16x8 av[4], bv[4];
#pragma unroll
            for (int m = 0; m < 4; ++m)
                av[m] = *(const bf16x8*)&As[(wr * 64 + m * 16 + fr) * 32 + fk];
#pragma unroll
            for (int n = 0; n < 4; ++n)
                bv[n] = *(const bf16x8*)&Bs[(wc * 64 + n * 16 + fr) * 32 + fk];
#pragma unroll
            for (int m = 0; m < 4; ++m)
#pragma unroll
                for (int n = 0; n < 4; ++n)
                    acc[m][n] = __builtin_amdgcn_mfma_f32_16x16x32_bf16(
                                    av[m], bv[n], acc[m][n], 0, 0, 0);
            __syncthreads();
        }
    }

    const int col_l = lane & 15;
    const int row_h = (lane >> 4) * 4;
#pragma unroll
    for (int m = 0; m < 4; ++m) {
#pragma unroll
        for (int j = 0; j < 4; ++j) {
            const int row = bm + wr * 64 + m * 16 + row_h + j;
#pragma unroll
            for (int n = 0; n < 4; ++n) {
                const int col = bn + wc * 64 + n * 16 + col_l;
                float v = acc[m][n][j];
                if (Cin)  v += Cin[(size_t)row * ldc + col];
                if (bias) v += bias[col];
                if (EPI == 1) {
                    float e = v > 0.f ? v : expm1f(v);
                    float sc = bng[col] * rsqrtf(bnv[col] + EPSV);
                    v = (e - bnm[col]) * sc + bnb[col];
                } else if (EPI == 2) {
                    v = fmaxf(v, 0.f);
                }
                if (WF32) Cf[(size_t)row * ldc + col] = v;
                if (WB16) Cb[(size_t)row * ldc + col] = f2b(v);
            }
        }
    }
}

template<int EPI>
__launch_bounds__(256)
__global__ void conv_gemm(int Lin, const u16* X, const u16* W, const float* bias,
                          const float* bng, const float* bnb, const float* bnm, const float* bnv,
                          u16* Y)
{
    const int t = blockIdx.z;
    int l0 = 0, k0 = 0, l1 = 0, k1 = 0, cnt = 0;
    for (int l = 0; l < Lin; ++l) {
        int k = t - 2 * l;
        if (k >= 0 && k < 3) { if (!cnt) { l0 = l; k0 = k; } else { l1 = l; k1 = k; } ++cnt; }
    }
    const size_t BH = (size_t)BATCH * HD, HH = (size_t)HD * HD;
    gemm_tile<EPI, false, true>(blockIdx.y * 128, blockIdx.x * 128,
        HD, X + l0 * BH, HD, W + k0 * HH, HD,
        cnt > 1 ? HD : 0, X + l1 * BH, HD, W + k1 * HH, HD,
        bias, nullptr, bng, bnb, bnm, bnv, nullptr, Y + (size_t)t * BH, HD);
}

// gi (z=0, K=512 from inp, C-init = gdec_t) and gh (z=1, K=1024) in one launch
__launch_bounds__(256)
__global__ void gru_gemms(int K_gi, const u16* inp_b, const u16* w_ih_b,
                          const u16* h_b, const u16* w_hh_b,
                          const float* gdec_t, const float* bias_gi,
                          const float* b_hh, float* gi, float* gh)
{
    if (blockIdx.z == 0)
        gemm_tile<0, true, false>(blockIdx.y * 128, blockIdx.x * 128,
            K_gi, inp_b, IND, w_ih_b, IND + HD,
            0, nullptr, 0, nullptr, 0,
            bias_gi, gdec_t, nullptr, nullptr, nullptr, nullptr,
            gi, nullptr, 3 * HD);
    else
        gemm_tile<0, true, false>(blockIdx.y * 128, blockIdx.x * 128,
            HD, h_b, HD, w_hh_b, HD,
            0, nullptr, 0, nullptr, 0,
            b_hh, nullptr, nullptr, nullptr, nullptr, nullptr,
            gh, nullptr, 3 * HD);
}

// h2x projection: inp = relu(h @ h2xw^T + b)
__launch_bounds__(256)
__global__ void h2x_gemm(const u16* h_b, const u16* wx, const float* xb, u16* inp)
{
    gemm_tile<2, false, true>(blockIdx.y * 128, blockIdx.x * 128,
        HD, h_b, HD, wx, HD,
        0, nullptr, 0, nullptr, 0,
        xb, nullptr, nullptr, nullptr, nullptr, nullptr,
        nullptr, inp, IND);
}

// ---------------------------------------------------------------------------
__global__ void pack_w(const float* __restrict__ cw, u16* __restrict__ wp)
{   // (H,H,3) raw [o,i,k] -> bf16 (3,H,H) [k][o][i]
    __shared__ float lds[768];
    const int o = blockIdx.x, t = threadIdx.x;
    const float* src = cw + (size_t)o * (HD * 3);
    for (int i0 = 0; i0 < HD; i0 += 256) {
#pragma unroll
        for (int r = 0; r < 3; ++r) lds[t + 256 * r] = src[i0 * 3 + t + 256 * r];
        __syncthreads();
#pragma unroll
        for (int k = 0; k < 3; ++k)
            wp[(size_t)k * HD * HD + (size_t)o * HD + i0 + t] = f2b(lds[t * 3 + k]);
        __syncthreads();
    }
}

__global__ void f32_to_b16(const float* __restrict__ s, u16* __restrict__ d, int n)
{
    int i = (blockIdx.x * 256 + threadIdx.x) * 8;
    if (i >= n) return;
    float4 a = *(const float4*)(s + i);
    float4 b = *(const float4*)(s + i + 4);
    u16x8 o;
    o[0] = f2b(a.x); o[1] = f2b(a.y); o[2] = f2b(a.z); o[3] = f2b(a.w);
    o[4] = f2b(b.x); o[5] = f2b(b.y); o[6] = f2b(b.z); o[7] = f2b(b.w);
    *(u16x8*)(d + i) = o;
}

// extra0[j] = 8190 * sum_{k<IND} w_ih[j,k]  (fp32-exact t=0 inp contribution)
__global__ void ext0_k(const float* __restrict__ w_ih, float* __restrict__ e0)
{
    const int j = blockIdx.x, lane = threadIdx.x;   // 64 lanes
    float s = 0.f;
    for (int k = lane; k < IND; k += 64) s += w_ih[(size_t)j * (IND + HD) + k];
    for (int off = 32; off; off >>= 1) s += __shfl_down(s, off);
    if (lane == 0) e0[j] = 8190.f * s;
}

__global__ void gru_cell(const float* __restrict__ gi, const float* __restrict__ gh,
                         const float* __restrict__ hp, float* __restrict__ ho,
                         u16* __restrict__ hb)
{
    const int idx = blockIdx.x * 256 + threadIdx.x;
    const int n = idx >> 10, o = idx & 1023;
    const size_t base = (size_t)n * 3 * HD + o;
    const float ir = gi[base], iz = gi[base + HD], in_ = gi[base + 2 * HD];
    const float hr = gh[base], hz = gh[base + HD], hn = gh[base + 2 * HD];
    const float r  = 1.f / (1.f + expf(-(ir + hr)));
    const float zg = 1.f / (1.f + expf(-(iz + hz)));
    const float nn = tanhf(in_ + r * hn);
    const float h  = (1.f - zg) * nn + zg * hp[idx];
    ho[idx] = h;
    hb[idx] = f2b(h);
}

// ---------------------------------------------------------------------------
extern "C" void kernel_launch(void* const* d_in, const int* in_sizes, int n_in,
                              void* d_out, int out_size, void* d_ws, size_t ws_size,
                              hipStream_t stream)
{
    (void)in_sizes; (void)n_in; (void)out_size; (void)ws_size;

    const float* z    = (const float*)d_in[0];
    const float* cw1  = (const float*)d_in[2];
    const float* cb1  = (const float*)d_in[3];
    const float* cw2  = (const float*)d_in[4];
    const float* cb2  = (const float*)d_in[5];
    const float* cw3  = (const float*)d_in[6];
    const float* cb3  = (const float*)d_in[7];
    const float* bn1g = (const float*)d_in[8];
    const float* bn1b = (const float*)d_in[9];
    const float* bn1m = (const float*)d_in[10];
    const float* bn1v = (const float*)d_in[11];
    const float* bn2g = (const float*)d_in[12];
    const float* bn2b = (const float*)d_in[13];
    const float* bn2m = (const float*)d_in[14];
    const float* bn2v = (const float*)d_in[15];
    const float* w_ih = (const float*)d_in[16];
    const float* w_hh = (const float*)d_in[17];
    const float* b_ih = (const float*)d_in[18];
    const float* b_hh = (const float*)d_in[19];
    const float* h2xw = (const float*)d_in[20];
    const float* h2xb = (const float*)d_in[21];
    const float* d2ow = (const float*)d_in[22];
    const float* d2ob = (const float*)d_in[23];
    const float* outw = (const float*)d_in[24];
    const float* outb = (const float*)d_in[25];

    const size_t HH = (size_t)HD * HD, BH = (size_t)BATCH * HD;
    const size_t B3H = (size_t)BATCH * 3 * HD;

    u16* wsb = (u16*)d_ws;
    size_t off = 0;
    auto A16 = [&](size_t n) { u16* p = wsb + off; off += n; return p; };
    u16* wp1   = A16(3 * HH);
    u16* wp2   = A16(3 * HH);
    u16* wp3   = A16(3 * HH);
    u16* wihb  = A16((size_t)3 * HD * (IND + HD));
    u16* whhb  = A16(3 * HH);
    u16* h2xbw = A16((size_t)IND * HD);
    u16* outwb = A16((size_t)OUTD * HD);
    u16* d2owb = A16((size_t)OUTD * HD);
    u16* zb    = A16(BH);
    u16* decab = A16(3 * BH);
    u16* decbb = A16(7 * BH);
    u16* dec3b = A16(15 * BH);
    u16* hsb   = A16(15 * BH);
    u16* inpb  = A16((size_t)BATCH * IND);
    float* wsf = (float*)(wsb + ((off + 1) & ~(size_t)1));
    size_t foff = 0;
    auto A32 = [&](size_t n) { float* p = wsf + foff; foff += n; return p; };
    float* gi    = A32(B3H);
    float* gh    = A32(B3H);
    float* h0f   = A32(BH);
    float* h1f   = A32(BH);
    float* extra0= A32(3 * HD);
    float* gdec  = A32((size_t)TSTEPS * B3H);   // 15 x 1024 x 3072 fp32 (~188 MB)

    pack_w<<<HD, 256, 0, stream>>>(cw1, wp1);
    pack_w<<<HD, 256, 0, stream>>>(cw2, wp2);
    pack_w<<<HD, 256, 0, stream>>>(cw3, wp3);
    auto cvt = [&](const float* s, u16* d, size_t n) {
        f32_to_b16<<<(unsigned)(n / 2048), 256, 0, stream>>>(s, d, (int)n);
    };
    cvt(z, zb, BH);
    cvt(w_ih, wihb, (size_t)3 * HD * (IND + HD));
    cvt(w_hh, whhb, 3 * HH);
    cvt(h2xw, h2xbw, (size_t)IND * HD);
    cvt(outw, outwb, (size_t)OUTD * HD);
    cvt(d2ow, d2owb, (size_t)OUTD * HD);
    ext0_k<<<3 * HD, 64, 0, stream>>>(w_ih, extra0);

    conv_gemm<1><<<dim3(8, 8, 3), 256, 0, stream>>>(1, zb, wp1, cb1,
        bn1g, bn1b, bn1m, bn1v, decab);
    conv_gemm<1><<<dim3(8, 8, 7), 256, 0, stream>>>(3, decab, wp2, cb2,
        bn2g, bn2b, bn2m, bn2v, decbb);
    conv_gemm<0><<<dim3(8, 8, 15), 256, 0, stream>>>(7, decbb, wp3, cb3,
        nullptr, nullptr, nullptr, nullptr, dec3b);

    // gdec[t] = dec_tbh @ w_ih[:,512:]^T + b_ih  for all t (parallel, off the chain)
    gemm256<<<dim3((TSTEPS * BATCH / 256) * (3 * HD / 256)), 512, 0, stream>>>(
        3 * HD / 256, HD / 64,
        dec3b, wihb + IND, b_ih, gdec, HD, IND + HD, 3 * HD);

    for (int t = 0; t < TSTEPS; ++t) {
        const u16* hbp   = t ? hsb + (size_t)(t - 1) * BH : zb;
        const float* hpf = (t == 0) ? z : (((t - 1) & 1) ? h1f : h0f);
        float* hwf = (t & 1) ? h1f : h0f;
        gru_gemms<<<dim3(24, 8, 2), 256, 0, stream>>>(
            t ? IND : 0, inpb, wihb, hbp, whhb,
            gdec + (size_t)t * B3H, t ? nullptr : extra0, b_hh, gi, gh);
        gru_cell<<<(BATCH * HD) / 256, 256, 0, stream>>>(gi, gh, hpf, hwf,
            hsb + (size_t)t * BH);
        if (t < TSTEPS - 1)
            h2x_gemm<<<dim3(4, 8), 256, 0, stream>>>(
                hsb + (size_t)t * BH, h2xbw, h2xb, inpb);
    }

    // output projections
    float* out0 = (float*)d_out;
    float* out1 = out0 + (size_t)TSTEPS * BATCH * OUTD;
    const int nbn = OUTD / 256;                       // 32
    const int nwg = (TSTEPS * BATCH / 256) * nbn;     // 1920
    gemm256<<<dim3(nwg), 512, 0, stream>>>(nbn, HD / 64,
        hsb, outwb, outb, out0, HD, HD, OUTD);
    gemm256<<<dim3(nwg), 512, 0, stream>>>(nbn, HD / 64,
        dec3b, d2owb, d2ob, out1, HD, HD, OUTD);
}

// Round 7
// 1668.239 us; speedup vs baseline: 1.4229x; 1.2630x over previous
//
#include <hip/hip_runtime.h>
#include <math.h>

// HybridDecoder. B=1024 H=1024 IN=512 OUT=8192 T=15.
// R7: GRU step = 2 launches: h2x_k (128 blk) + gih_cell (256 blk, gh+gi in regs,
//     cell fused in epilogue -> gi/gh never hit HBM). gdec stored bf16.
// conv_transpose identity: y[n,o,t] = sum_{2l+k=t} x[n,i,l] * W[o,i,k]

#define HD    1024
#define BATCH 1024
#define IND   512
#define OUTD  8192
#define TSTEPS 15
#define EPSV  1e-5f

typedef unsigned short u16;
typedef __attribute__((ext_vector_type(8))) short bf16x8;
typedef __attribute__((ext_vector_type(8))) unsigned short u16x8;
typedef __attribute__((ext_vector_type(4))) unsigned short u16x4;
typedef __attribute__((ext_vector_type(4))) float f32x4;

__device__ __forceinline__ u16 f2b(float f) {          // fp32 -> bf16 RNE
    union { float f; unsigned u; } x; x.f = f;
    unsigned r = x.u + 0x7fffu + ((x.u >> 16) & 1u);
    return (u16)(r >> 16);
}
__device__ __forceinline__ float b2f(u16 v) {
    union { unsigned u; float f; } x; x.u = ((unsigned)v) << 16; return x.f;
}

typedef __attribute__((address_space(1))) const void gas_t;
typedef __attribute__((address_space(3))) void las_t;
__device__ __forceinline__ void gload_lds16(const u16* g, u16* l) {
    __builtin_amdgcn_global_load_lds((gas_t*)g, (las_t*)l, 16, 0, 0);
}

// ===========================================================================
// 256x256 GEMM (bf16 in, fp32 or bf16 out): C = A@B^T + bias.
// 512 thr = 8 waves (2M x 4N); BK=64 double-buffered (128 KiB LDS).
// stage(kt+1) at tile top -> full-tile cover -> single {vmcnt(0); barrier}/tile.
// XOR swizzle on global-source + ds_read. Coalesced LDS-bounce epilogue.
// ===========================================================================
template<int OUTB>
__launch_bounds__(512, 2)
__global__ void gemm256(int nbn, int nk,
    const u16* __restrict__ A, const u16* __restrict__ B,
    const float* __restrict__ bias, float* __restrict__ Cf,
    u16* __restrict__ Cb, int lda, int ldb, int ldc)
{
    // bijective XCD swizzle (m204)
    const int nwg = gridDim.x;
    const int q = nwg >> 3, r = nwg & 7;
    const int xcd = blockIdx.x & 7, idx = blockIdx.x >> 3;
    const int wg = (xcd < r ? xcd * (q + 1) : r * (q + 1) + (xcd - r) * q) + idx;
    const int bm = (wg / nbn) * 256;
    const int bn = (wg % nbn) * 256;

    __shared__ __align__(16) u16 smem[2][2][256 * 64];   // [A/B][buf][.]
    u16 (*As)[256 * 64] = smem[0];
    u16 (*Bs)[256 * 64] = smem[1];

    const int tid = threadIdx.x;
    const int w = tid >> 6, l = tid & 63;
    const int wr = w >> 2, wc = w & 3;       // 2M x 4N wave grid
    const int srow = l >> 3;                 // staging row in 8-row chunk
    const int scb  = (l & 7) ^ srow;         // swizzled SOURCE col-block
    const int fr = l & 15, fcb = l >> 4, swz = l & 7;

    const u16* Ag = A + (size_t)bm * lda;
    const u16* Bg = B + (size_t)bn * ldb;

    auto stage = [&](int b, int kt) {        // 8 gload_lds / thread
        const int k0 = kt * 64 + scb * 8;
#pragma unroll
        for (int rr = 0; rr < 4; ++rr)
            gload_lds16(Ag + (size_t)(rr * 64 + w * 8 + srow) * lda + k0,
                        &As[b][(rr * 64 + w * 8) * 64]);
#pragma unroll
        for (int rr = 0; rr < 4; ++rr)
            gload_lds16(Bg + (size_t)(rr * 64 + w * 8 + srow) * ldb + k0,
                        &Bs[b][(rr * 64 + w * 8) * 64]);
    };

    f32x4 acc[8][4];
#pragma unroll
    for (int m = 0; m < 8; ++m)
#pragma unroll
        for (int n = 0; n < 4; ++n) acc[m][n] = (f32x4){0.f, 0.f, 0.f, 0.f};

    stage(0, 0);
    asm volatile("s_waitcnt vmcnt(0)" ::: "memory");
    asm volatile("s_barrier" ::: "memory");

    for (int kt = 0; kt < nk; ++kt) {
        const int c = kt & 1;
        if (kt + 1 < nk) stage(c ^ 1, kt + 1);    // full-tile cover before wait
#pragma unroll
        for (int ks = 0; ks < 2; ++ks) {
            bf16x8 av[8], bv[4];
#pragma unroll
            for (int m = 0; m < 8; ++m)
                av[m] = *(const bf16x8*)&As[c][
                    (wr * 128 + m * 16 + fr) * 64 + (((ks * 4 + fcb) ^ swz) * 8)];
#pragma unroll
            for (int n = 0; n < 4; ++n)
                bv[n] = *(const bf16x8*)&Bs[c][
                    (wc * 64 + n * 16 + fr) * 64 + (((ks * 4 + fcb) ^ swz) * 8)];
            __builtin_amdgcn_s_setprio(1);
#pragma unroll
            for (int m = 0; m < 8; ++m)
#pragma unroll
                for (int n = 0; n < 4; ++n)
                    acc[m][n] = __builtin_amdgcn_mfma_f32_16x16x32_bf16(
                                    av[m], bv[n], acc[m][n], 0, 0, 0);
            __builtin_amdgcn_s_setprio(0);
        }
        asm volatile("s_waitcnt vmcnt(0)" ::: "memory");   // kt+1 staged
        asm volatile("s_barrier" ::: "memory");            // all reads of c done
    }

    // ---- epilogue: LDS bounce -> coalesced streams ----
    float* fsm = (float*)smem;               // 128 x 256 f32 = 128 KiB
    const int row_h = (l >> 4) * 4;
#pragma unroll 1
    for (int hh = 0; hh < 2; ++hh) {
        __syncthreads();
        if (wr == hh) {
#pragma unroll
            for (int m = 0; m < 8; ++m)
#pragma unroll
                for (int j = 0; j < 4; ++j) {
                    const int rl = m * 16 + row_h + j;
#pragma unroll
                    for (int n = 0; n < 4; ++n)
                        fsm[rl * 256 + wc * 64 + n * 16 + fr] = acc[m][n][j];
                }
        }
        __syncthreads();
#pragma unroll
        for (int it = 0; it < 16; ++it) {
            const int fid = it * 512 + tid;          // 0..8191 float4 ids
            const int rl = fid >> 6;
            const int cf = (fid & 63) * 4;
            float4 v = *(const float4*)&fsm[rl * 256 + cf];
            v.x += bias[bn + cf + 0];
            v.y += bias[bn + cf + 1];
            v.z += bias[bn + cf + 2];
            v.w += bias[bn + cf + 3];
            if (OUTB) {
                u16x4 o;
                o[0] = f2b(v.x); o[1] = f2b(v.y); o[2] = f2b(v.z); o[3] = f2b(v.w);
                *(u16x4*)&Cb[(size_t)(bm + hh * 128 + rl) * ldc + bn + cf] = o;
            } else {
                *(float4*)&Cf[(size_t)(bm + hh * 128 + rl) * ldc + bn + cf] = v;
            }
        }
    }
}

// ===========================================================================
// 128x128 m97-structure tile for conv GEMMs (dual (l,k) pair)
// ===========================================================================
template<int EPI>
__device__ __forceinline__ void gemm_tile(
    int bm, int bn,
    int K1, const u16* A1, int lda1, const u16* B1, int ldb1,
    int K2, const u16* A2, int lda2, const u16* B2, int ldb2,
    const float* bias,
    const float* bng, const float* bnb, const float* bnm, const float* bnv,
    u16* Cb, int ldc)
{
    __shared__ __align__(16) u16 As[128 * 32];
    __shared__ __align__(16) u16 Bs[128 * 32];

    const int tid  = threadIdx.x;
    const int lane = tid & 63;
    const int w    = tid >> 6;
    const int wr   = w >> 1, wc = w & 1;
    const int r_in = lane >> 2;
    const int c_in = (lane & 3) * 8;

    f32x4 acc[4][4];
#pragma unroll
    for (int m = 0; m < 4; ++m)
#pragma unroll
        for (int n = 0; n < 4; ++n) acc[m][n] = (f32x4){0.f, 0.f, 0.f, 0.f};

#pragma unroll 1
    for (int pair = 0; pair < 2; ++pair) {
        const int K = pair ? K2 : K1;
        if (K == 0) continue;
        const int lda = pair ? lda2 : lda1;
        const int ldb = pair ? ldb2 : ldb1;
        const u16* Ag = (pair ? A2 : A1) + (size_t)bm * lda;
        const u16* Bg = (pair ? B2 : B1) + (size_t)bn * ldb;

        for (int k0 = 0; k0 < K; k0 += 32) {
#pragma unroll
            for (int i = 0; i < 2; ++i) {
                gload_lds16(Ag + (size_t)(i * 64 + w * 16 + r_in) * lda + k0 + c_in,
                            &As[i * 2048 + w * 512]);
                gload_lds16(Bg + (size_t)(i * 64 + w * 16 + r_in) * ldb + k0 + c_in,
                            &Bs[i * 2048 + w * 512]);
            }
            __syncthreads();

            const int fr = lane & 15;
            const int fk = (lane >> 4) * 8;
            bf16x8 av[4], bv[4];
#pragma unroll
            for (int m = 0; m < 4; ++m)
                av[m] = *(const bf16x8*)&As[(wr * 64 + m * 16 + fr) * 32 + fk];
#pragma unroll
            for (int n = 0; n < 4; ++n)
                bv[n] = *(const bf16x8*)&Bs[(wc * 64 + n * 16 + fr) * 32 + fk];
#pragma unroll
            for (int m = 0; m < 4; ++m)
#pragma unroll
                for (int n = 0; n < 4; ++n)
                    acc[m][n] = __builtin_amdgcn_mfma_f32_16x16x32_bf16(
                                    av[m], bv[n], acc[m][n], 0, 0, 0);
            __syncthreads();
        }
    }

    const int col_l = lane & 15;
    const int row_h = (lane >> 4) * 4;
#pragma unroll
    for (int m = 0; m < 4; ++m) {
#pragma unroll
        for (int j = 0; j < 4; ++j) {
            const int row = bm + wr * 64 + m * 16 + row_h + j;
#pragma unroll
            for (int n = 0; n < 4; ++n) {
                const int col = bn + wc * 64 + n * 16 + col_l;
                float v = acc[m][n][j] + bias[col];
                if (EPI == 1) {
                    float e = v > 0.f ? v : expm1f(v);
                    float sc = bng[col] * rsqrtf(bnv[col] + EPSV);
                    v = (e - bnm[col]) * sc + bnb[col];
                }
                Cb[(size_t)row * ldc + col] = f2b(v);
            }
        }
    }
}

template<int EPI>
__launch_bounds__(256)
__global__ void conv_gemm(int Lin, const u16* X, const u16* W, const float* bias,
                          const float* bng, const float* bnb, const float* bnm, const float* bnv,
                          u16* Y)
{
    const int t = blockIdx.z;
    int l0 = 0, k0 = 0, l1 = 0, k1 = 0, cnt = 0;
    for (int l = 0; l < Lin; ++l) {
        int k = t - 2 * l;
        if (k >= 0 && k < 3) { if (!cnt) { l0 = l; k0 = k; } else { l1 = l; k1 = k; } ++cnt; }
    }
    const size_t BH = (size_t)BATCH * HD, HH = (size_t)HD * HD;
    gemm_tile<EPI>(blockIdx.y * 128, blockIdx.x * 128,
        HD, X + l0 * BH, HD, W + k0 * HH, HD,
        cnt > 1 ? HD : 0, X + l1 * BH, HD, W + k1 * HH, HD,
        bias, bng, bnb, bnm, bnv, Y + (size_t)t * BH, HD);
}

// ===========================================================================
// Fused GRU step: gh (K=1024) + gi (K=512) + cell, all in registers.
// Block = 64 batch rows x 64 h-cols; grid (16,16)=256 blocks, 256 thr.
// Acc sets: ar,az (gi+gh summed), ain, ahn (separate for the n-gate).
// ===========================================================================
#define KTILE(Ag, lda_, Bg, ldb_, k0_, ACC2)                                      \
  {                                                                               \
    const int k0 = (k0_);                                                         \
    gload_lds16((Ag) + (size_t)(tid >> 2) * (lda_) + k0 + (tid & 3) * 8,          \
                &As[tid * 8]);                                                    \
    _Pragma("unroll")                                                             \
    for (int i_ = 0; i_ < 3; ++i_) {                                              \
      const int u_ = tid + i_ * 256;                                              \
      gload_lds16((Bg) + (size_t)((u_ >> 8) * HD + bn + ((u_ & 255) >> 2)) * (ldb_)\
                       + k0 + (u_ & 3) * 8,                                       \
                  &Bs[u_ * 8]);                                                   \
    }                                                                             \
    __syncthreads();                                                              \
    {                                                                             \
      bf16x8 av0 = *(const bf16x8*)&As[(wr * 32 + fr) * 32 + fk];                 \
      bf16x8 av1 = *(const bf16x8*)&As[(wr * 32 + 16 + fr) * 32 + fk];            \
      _Pragma("unroll")                                                           \
      for (int n_ = 0; n_ < 2; ++n_) {                                            \
        const int bo = (wc * 32 + n_ * 16 + fr) * 32 + fk;                        \
        bf16x8 bv = *(const bf16x8*)&Bs[bo];                                      \
        ar[0][n_] = __builtin_amdgcn_mfma_f32_16x16x32_bf16(av0, bv, ar[0][n_], 0, 0, 0); \
        ar[1][n_] = __builtin_amdgcn_mfma_f32_16x16x32_bf16(av1, bv, ar[1][n_], 0, 0, 0); \
        bv = *(const bf16x8*)&Bs[2048 + bo];                                      \
        az[0][n_] = __builtin_amdgcn_mfma_f32_16x16x32_bf16(av0, bv, az[0][n_], 0, 0, 0); \
        az[1][n_] = __builtin_amdgcn_mfma_f32_16x16x32_bf16(av1, bv, az[1][n_], 0, 0, 0); \
        bv = *(const bf16x8*)&Bs[4096 + bo];                                      \
        ACC2[0][n_] = __builtin_amdgcn_mfma_f32_16x16x32_bf16(av0, bv, ACC2[0][n_], 0, 0, 0); \
        ACC2[1][n_] = __builtin_amdgcn_mfma_f32_16x16x32_bf16(av1, bv, ACC2[1][n_], 0, 0, 0); \
      }                                                                           \
    }                                                                             \
    __syncthreads();                                                              \
  }

__launch_bounds__(256)
__global__ void gih_cell(int t,
    const u16* __restrict__ inpb,  const u16* __restrict__ wih,
    const u16* __restrict__ hbp,   const u16* __restrict__ whh,
    const u16* __restrict__ gdect, const float* __restrict__ extra0,
    const float* __restrict__ b_hh, const float* __restrict__ hp,
    float* __restrict__ hf, u16* __restrict__ hsbt)
{
    const int bm = blockIdx.y * 64;     // batch rows
    const int bn = blockIdx.x * 64;     // h cols
    __shared__ __align__(16) u16 As[64 * 32];
    __shared__ __align__(16) u16 Bs[3 * 64 * 32];

    const int tid = threadIdx.x, l = tid & 63, w = tid >> 6;
    const int wr = w >> 1, wc = w & 1;
    const int fr = l & 15, fk = (l >> 4) * 8;

    f32x4 ar[2][2], az[2][2], ain[2][2], ahn[2][2];
#pragma unroll
    for (int m = 0; m < 2; ++m)
#pragma unroll
        for (int n = 0; n < 2; ++n) {
            ar[m][n] = (f32x4){0.f, 0.f, 0.f, 0.f};
            az[m][n] = (f32x4){0.f, 0.f, 0.f, 0.f};
            ain[m][n] = (f32x4){0.f, 0.f, 0.f, 0.f};
            ahn[m][n] = (f32x4){0.f, 0.f, 0.f, 0.f};
        }

    const u16* Ah = hbp + (size_t)bm * HD;        // gh A-panel
    const u16* Ai = inpb + (size_t)bm * IND;      // gi A-panel
    // pass 1: gh over K=1024
    for (int kt = 0; kt < 32; ++kt)
        KTILE(Ah, HD, whh, HD, kt * 32, ahn);
    // pass 2: gi over K=512 (skip at t=0: inp contribution folded into extra0)
    if (t > 0)
        for (int kt = 0; kt < 16; ++kt)
            KTILE(Ai, IND, wih, (IND + HD), kt * 32, ain);

    // ---- cell epilogue ----
    const int rh = (l >> 4) * 4;
#pragma unroll
    for (int m = 0; m < 2; ++m)
#pragma unroll
        for (int n = 0; n < 2; ++n)
#pragma unroll
            for (int j = 0; j < 4; ++j) {
                const int R = bm + wr * 32 + m * 16 + rh + j;
                const int C = bn + wc * 32 + n * 16 + fr;
                const size_t g3 = (size_t)R * (3 * HD);
                float gr  = ar[m][n][j] + b2f(gdect[g3 + C])          + b_hh[C];
                float gz  = az[m][n][j] + b2f(gdect[g3 + HD + C])     + b_hh[HD + C];
                float gin = ain[m][n][j] + b2f(gdect[g3 + 2 * HD + C]);
                float ghn = ahn[m][n][j] + b_hh[2 * HD + C];
                if (extra0) {
                    gr  += extra0[C];
                    gz  += extra0[HD + C];
                    gin += extra0[2 * HD + C];
                }
                const float rg = 1.f / (1.f + expf(-gr));
                const float zg = 1.f / (1.f + expf(-gz));
                const float nn = tanhf(gin + rg * ghn);
                const float h  = (1.f - zg) * nn + zg * hp[(size_t)R * HD + C];
                hf[(size_t)R * HD + C] = h;
                hsbt[(size_t)R * HD + C] = f2b(h);
            }
}

// ===========================================================================
// h2x: inp = relu(h @ h2xw^T + b).  Block 64 rows x 64 cols; grid (8,16)=128.
// ===========================================================================
__launch_bounds__(256)
__global__ void h2x_k(const u16* __restrict__ hbp, const u16* __restrict__ wx,
                      const float* __restrict__ xb, u16* __restrict__ inp)
{
    const int bm = blockIdx.y * 64;   // batch rows
    const int bn = blockIdx.x * 64;   // IND cols
    __shared__ __align__(16) u16 As[64 * 32];
    __shared__ __align__(16) u16 Bs[64 * 32];

    const int tid = threadIdx.x, l = tid & 63, w = tid >> 6;
    const int wr = w >> 1, wc = w & 1;
    const int fr = l & 15, fk = (l >> 4) * 8;

    f32x4 acc[2][2];
#pragma unroll
    for (int m = 0; m < 2; ++m)
#pragma unroll
        for (int n = 0; n < 2; ++n) acc[m][n] = (f32x4){0.f, 0.f, 0.f, 0.f};

    const u16* Ag = hbp + (size_t)bm * HD;
    const u16* Bg = wx + (size_t)bn * HD;
    for (int kt = 0; kt < 32; ++kt) {
        const int k0 = kt * 32;
        gload_lds16(Ag + (size_t)(tid >> 2) * HD + k0 + (tid & 3) * 8, &As[tid * 8]);
        gload_lds16(Bg + (size_t)(tid >> 2) * HD + k0 + (tid & 3) * 8, &Bs[tid * 8]);
        __syncthreads();
        bf16x8 av0 = *(const bf16x8*)&As[(wr * 32 + fr) * 32 + fk];
        bf16x8 av1 = *(const bf16x8*)&As[(wr * 32 + 16 + fr) * 32 + fk];
#pragma unroll
        for (int n = 0; n < 2; ++n) {
            bf16x8 bv = *(const bf16x8*)&Bs[(wc * 32 + n * 16 + fr) * 32 + fk];
            acc[0][n] = __builtin_amdgcn_mfma_f32_16x16x32_bf16(av0, bv, acc[0][n], 0, 0, 0);
            acc[1][n] = __builtin_amdgcn_mfma_f32_16x16x32_bf16(av1, bv, acc[1][n], 0, 0, 0);
        }
        __syncthreads();
    }
    const int rh = (l >> 4) * 4;
#pragma unroll
    for (int m = 0; m < 2; ++m)
#pragma unroll
        for (int n = 0; n < 2; ++n)
#pragma unroll
            for (int j = 0; j < 4; ++j) {
                const int R = bm + wr * 32 + m * 16 + rh + j;
                const int C = bn + wc * 32 + n * 16 + fr;
                inp[(size_t)R * IND + C] = f2b(fmaxf(acc[m][n][j] + xb[C], 0.f));
            }
}

// ---------------------------------------------------------------------------
__global__ void pack_w(const float* __restrict__ cw, u16* __restrict__ wp)
{   // (H,H,3) raw [o,i,k] -> bf16 (3,H,H) [k][o][i]
    __shared__ float lds[768];
    const int o = blockIdx.x, t = threadIdx.x;
    const float* src = cw + (size_t)o * (HD * 3);
    for (int i0 = 0; i0 < HD; i0 += 256) {
#pragma unroll
        for (int r = 0; r < 3; ++r) lds[t + 256 * r] = src[i0 * 3 + t + 256 * r];
        __syncthreads();
#pragma unroll
        for (int k = 0; k < 3; ++k)
            wp[(size_t)k * HD * HD + (size_t)o * HD + i0 + t] = f2b(lds[t * 3 + k]);
        __syncthreads();
    }
}

__global__ void f32_to_b16(const float* __restrict__ s, u16* __restrict__ d, int n)
{
    int i = (blockIdx.x * 256 + threadIdx.x) * 8;
    if (i >= n) return;
    float4 a = *(const float4*)(s + i);
    float4 b = *(const float4*)(s + i + 4);
    u16x8 o;
    o[0] = f2b(a.x); o[1] = f2b(a.y); o[2] = f2b(a.z); o[3] = f2b(a.w);
    o[4] = f2b(b.x); o[5] = f2b(b.y); o[6] = f2b(b.z); o[7] = f2b(b.w);
    *(u16x8*)(d + i) = o;
}

// extra0[j] = 8190 * sum_{k<IND} w_ih[j,k]  (fp32-exact t=0 inp contribution)
__global__ void ext0_k(const float* __restrict__ w_ih, float* __restrict__ e0)
{
    const int j = blockIdx.x, lane = threadIdx.x;   // 64 lanes
    float s = 0.f;
    for (int k = lane; k < IND; k += 64) s += w_ih[(size_t)j * (IND + HD) + k];
    for (int off = 32; off; off >>= 1) s += __shfl_down(s, off);
    if (lane == 0) e0[j] = 8190.f * s;
}

// ---------------------------------------------------------------------------
extern "C" void kernel_launch(void* const* d_in, const int* in_sizes, int n_in,
                              void* d_out, int out_size, void* d_ws, size_t ws_size,
                              hipStream_t stream)
{
    (void)in_sizes; (void)n_in; (void)out_size; (void)ws_size;

    const float* z    = (const float*)d_in[0];
    const float* cw1  = (const float*)d_in[2];
    const float* cb1  = (const float*)d_in[3];
    const float* cw2  = (const float*)d_in[4];
    const float* cb2  = (const float*)d_in[5];
    const float* cw3  = (const float*)d_in[6];
    const float* cb3  = (const float*)d_in[7];
    const float* bn1g = (const float*)d_in[8];
    const float* bn1b = (const float*)d_in[9];
    const float* bn1m = (const float*)d_in[10];
    const float* bn1v = (const float*)d_in[11];
    const float* bn2g = (const float*)d_in[12];
    const float* bn2b = (const float*)d_in[13];
    const float* bn2m = (const float*)d_in[14];
    const float* bn2v = (const float*)d_in[15];
    const float* w_ih = (const float*)d_in[16];
    const float* w_hh = (const float*)d_in[17];
    const float* b_ih = (const float*)d_in[18];
    const float* b_hh = (const float*)d_in[19];
    const float* h2xw = (const float*)d_in[20];
    const float* h2xb = (const float*)d_in[21];
    const float* d2ow = (const float*)d_in[22];
    const float* d2ob = (const float*)d_in[23];
    const float* outw = (const float*)d_in[24];
    const float* outb = (const float*)d_in[25];

    const size_t HH = (size_t)HD * HD, BH = (size_t)BATCH * HD;
    const size_t B3H = (size_t)BATCH * 3 * HD;

    u16* wsb = (u16*)d_ws;
    size_t off = 0;
    auto A16 = [&](size_t n) { u16* p = wsb + off; off += n; return p; };
    u16* wp1   = A16(3 * HH);
    u16* wp2   = A16(3 * HH);
    u16* wp3   = A16(3 * HH);
    u16* wihb  = A16((size_t)3 * HD * (IND + HD));
    u16* whhb  = A16(3 * HH);
    u16* h2xbw = A16((size_t)IND * HD);
    u16* outwb = A16((size_t)OUTD * HD);
    u16* d2owb = A16((size_t)OUTD * HD);
    u16* zb    = A16(BH);
    u16* decab = A16(3 * BH);
    u16* decbb = A16(7 * BH);
    u16* dec3b = A16(15 * BH);
    u16* hsb   = A16(15 * BH);
    u16* inpb  = A16((size_t)BATCH * IND);
    u16* gdecb = A16((size_t)TSTEPS * B3H);     // bf16 gdec (~94 MB)
    float* wsf = (float*)(wsb + ((off + 1) & ~(size_t)1));
    size_t foff = 0;
    auto A32 = [&](size_t n) { float* p = wsf + foff; foff += n; return p; };
    float* h0f   = A32(BH);
    float* h1f   = A32(BH);
    float* extra0= A32(3 * HD);

    pack_w<<<HD, 256, 0, stream>>>(cw1, wp1);
    pack_w<<<HD, 256, 0, stream>>>(cw2, wp2);
    pack_w<<<HD, 256, 0, stream>>>(cw3, wp3);
    auto cvt = [&](const float* s, u16* d, size_t n) {
        f32_to_b16<<<(unsigned)(n / 2048), 256, 0, stream>>>(s, d, (int)n);
    };
    cvt(z, zb, BH);
    cvt(w_ih, wihb, (size_t)3 * HD * (IND + HD));
    cvt(w_hh, whhb, 3 * HH);
    cvt(h2xw, h2xbw, (size_t)IND * HD);
    cvt(outw, outwb, (size_t)OUTD * HD);
    cvt(d2ow, d2owb, (size_t)OUTD * HD);
    ext0_k<<<3 * HD, 64, 0, stream>>>(w_ih, extra0);

    conv_gemm<1><<<dim3(8, 8, 3), 256, 0, stream>>>(1, zb, wp1, cb1,
        bn1g, bn1b, bn1m, bn1v, decab);
    conv_gemm<1><<<dim3(8, 8, 7), 256, 0, stream>>>(3, decab, wp2, cb2,
        bn2g, bn2b, bn2m, bn2v, decbb);
    conv_gemm<0><<<dim3(8, 8, 15), 256, 0, stream>>>(7, decbb, wp3, cb3,
        nullptr, nullptr, nullptr, nullptr, dec3b);

    // gdec[t] = dec_tbh @ w_ih[:,512:]^T + b_ih  for all t (parallel, bf16 out)
    gemm256<1><<<dim3((TSTEPS * BATCH / 256) * (3 * HD / 256)), 512, 0, stream>>>(
        3 * HD / 256, HD / 64,
        dec3b, wihb + IND, b_ih, nullptr, gdecb, HD, IND + HD, 3 * HD);

    // ---- GRU chain: 2 launches per step ----
    for (int t = 0; t < TSTEPS; ++t) {
        const u16* hbp   = t ? hsb + (size_t)(t - 1) * BH : zb;
        const float* hpf = (t == 0) ? z : (((t - 1) & 1) ? h1f : h0f);
        float* hwf = (t & 1) ? h1f : h0f;
        if (t > 0)
            h2x_k<<<dim3(8, 16), 256, 0, stream>>>(hbp, h2xbw, h2xb, inpb);
        gih_cell<<<dim3(16, 16), 256, 0, stream>>>(t,
            inpb, wihb, hbp, whhb, gdecb + (size_t)t * B3H,
            t ? nullptr : extra0, b_hh, hpf, hwf, hsb + (size_t)t * BH);
    }

    // output projections
    float* out0 = (float*)d_out;
    float* out1 = out0 + (size_t)TSTEPS * BATCH * OUTD;
    const int nbn = OUTD / 256;                       // 32
    const int nwg = (TSTEPS * BATCH / 256) * nbn;     // 1920
    gemm256<0><<<dim3(nwg), 512, 0, stream>>>(nbn, HD / 64,
        hsb, outwb, outb, out0, nullptr, HD, HD, OUTD);
    gemm256<0><<<dim3(nwg), 512, 0, stream>>>(nbn, HD / 64,
        dec3b, d2owb, d2ob, out1, nullptr, HD, HD, OUTD);
}